// Round 3
// baseline (2560.794 us; speedup 1.0000x reference)
//
#include <hip/hip_runtime.h>
#include <math.h>

// Problem constants
constexpr int Tn  = 2048;  // time
constexpr int FCn = 512;   // context feats (g)
constexpr int FXn = 512;   // encoding feats (x)
constexpr int SXW = 72;    // LDS stride (bf16 elems) for sX/sW chunks (64 + 8)
constexpr int SYC = 136;   // LDS stride (bf16 elems) for sY/sC (128 + 8)
constexpr int SZS = 132;   // LDS stride (fp32) for sZ

typedef __attribute__((ext_vector_type(8))) short  bf16x8;
typedef __attribute__((ext_vector_type(4))) float  f32x4;

// truncating fp32->bf16 pack: one v_perm_b32 per 2 elems
__device__ __forceinline__ unsigned pk2(float a, float b) {
  return __builtin_amdgcn_perm(__float_as_uint(b), __float_as_uint(a), 0x07060302u);
}
__device__ __forceinline__ uint4 pack8(float4 a, float4 b) {
  uint4 rv;
  rv.x = pk2(a.x, a.y); rv.y = pk2(a.z, a.w);
  rv.z = pk2(b.x, b.y); rv.w = pk2(b.z, b.w);
  return rv;
}

__global__ void zero4(float* out) {
  if (threadIdx.x < 4) out[threadIdx.x] = 0.0f;
}

__global__ void finalize4(float* out) {
  int k = threadIdx.x;
  if (k < 4) out[k] *= 1.0f / (128.0f * (float)(Tn - (1 << k)));
}

// prepass: W fp32 -> bf16 (trunc) into d_ws. 1M elems, 4 per thread.
__global__ void wconv(const float* __restrict__ W, unsigned short* __restrict__ Wh) {
  int i = blockIdx.x * 256 + threadIdx.x;
  float4 v = *((const float4*)W + i);
  uint2 p; p.x = pk2(v.x, v.y); p.y = pk2(v.z, v.w);
  *((uint2*)Wh + i) = p;
}

// One block per (k, t). Z[i,j] = sum_g C[i,t,g] * (sum_x W[k,g,x] X[j,t+tau,x])
// (bias dropped: j-independent bias cancels in Zdiag - lse), then row-lse and
// sum_i (Zdiag - lse) atomically accumulated into out[k].
// Register-rotate pipeline: phase n+1's global loads are issued immediately
// after phase n's LDS writes, so they fly during phase n's MFMA work and are
// drained (vmcnt(0) at __syncthreads) one full phase later.
template <bool WBF>
__global__ __launch_bounds__(512, 4)
void infonce_main(const float* __restrict__ Cp, const float* __restrict__ Xp,
                  const void* __restrict__ Wp, float* __restrict__ out)
{
  // LDS: sX [128][72] | sW [128][72] | sY [128][136]  = 71680 B (2 blocks/CU)
  // sC overlays sX+sW; sZ (fp32 [128][132]) + sRed overlay everything.
  __shared__ __align__(16) unsigned char smem[71680];
  unsigned short* sX = (unsigned short*)(smem);
  unsigned short* sW = (unsigned short*)(smem + 18432);
  unsigned short* sY = (unsigned short*)(smem + 36864);
  unsigned short* sC = (unsigned short*)(smem);
  float* sZ   = (float*)(smem);
  float* sRed = (float*)(smem + 67584);

  const int tid  = threadIdx.x;
  const int lane = tid & 63;
  const int wave = tid >> 6;     // 0..7
  const int r    = lane & 15;
  const int h    = lane >> 4;    // 0..3
  const int wr   = wave >> 1;    // 0..3  (32-row group)
  const int wc   = wave & 1;     // 0..1  (64-col group)

  // bijective chunked XCD swizzle: nwg = 8188 = 8*1023 + 4 (q=1023, r=4)
  const int orig = blockIdx.x;
  const int xcd  = orig & 7;
  const int loc  = orig >> 3;
  const int wg   = (xcd < 4) ? (xcd * 1024 + loc) : (4096 + (xcd - 4) * 1023 + loc);
  const int k    = wg & 3;
  const int t    = wg >> 2;
  const int tau  = 1 << k;       // TAU = {1,2,4,8}
  if (t >= Tn - tau) return;     // uniform early-exit, before any barrier

  const float* Cb = Cp + (size_t)t * FCn;             // C[i,t,g] = Cb[i*Tn*FCn + g]
  const float* Xb = Xp + (size_t)(t + tau) * FXn;     // X[j,s,x] = Xb[j*Tn*FXn + x]

  // staging coords: 4 threads per row, 16 elems each (64-col chunk)
  const int srow = tid >> 2;
  const int scol = (tid & 3) * 16;
  const float* xs = Xb + (size_t)srow * (Tn * FXn) + scol;
  unsigned short* xd = sX + srow * SXW + scol;
  unsigned short* wd = sW + srow * SXW + scol;
  // W source (bf16 in ws, or fp32 input)
  const unsigned short* wsh = WBF
      ? ((const unsigned short*)Wp + (size_t)k * (FCn * FXn) + (size_t)srow * FXn + scol)
      : nullptr;
  const float* wsf = WBF
      ? nullptr
      : ((const float*)Wp + (size_t)k * (FCn * FXn) + (size_t)srow * FXn + scol);
  // C staging coords: 16 threads per row, 8 elems each, 32 rows per rep
  const int crow0 = tid >> 4;            // 0..31
  const int ccol  = (tid & 15) * 8;
  const float* cs = Cb + (size_t)crow0 * (Tn * FCn) + ccol;
  unsigned short* cd = sC + crow0 * SYC + ccol;

  // prefetch registers
  float4 px[4];            // X chunk: 16 fp32
  float4 pwf[4];           // W chunk fp32 path
  uint4  pwb[2];           // W chunk bf16 path
  float4 pc[8];            // C chunk: 32 fp32

  auto loadX = [&](int xc) {
    const float4* p = (const float4*)(xs + xc * 64);
    px[0] = p[0]; px[1] = p[1]; px[2] = p[2]; px[3] = p[3];
  };
  auto loadW = [&](int gc, int xc) {
    if constexpr (WBF) {
      const uint4* p = (const uint4*)(wsh + (size_t)(gc * 128) * FXn + xc * 64);
      pwb[0] = p[0]; pwb[1] = p[1];
    } else {
      const float4* p = (const float4*)(wsf + (size_t)(gc * 128) * FXn + xc * 64);
      pwf[0] = p[0]; pwf[1] = p[1]; pwf[2] = p[2]; pwf[3] = p[3];
    }
  };
  auto loadC = [&](int gc) {
#pragma unroll
    for (int rr = 0; rr < 4; ++rr) {
      const float4* p = (const float4*)(cs + (size_t)rr * 32 * (Tn * FCn) + gc * 128);
      pc[2 * rr]     = p[0];
      pc[2 * rr + 1] = p[1];
    }
  };

  f32x4 zacc[2][4];
#pragma unroll
  for (int a = 0; a < 2; ++a)
#pragma unroll
    for (int b = 0; b < 4; ++b) zacc[a][b] = f32x4{0.f, 0.f, 0.f, 0.f};

  loadX(0); loadW(0, 0);   // prologue prefetch

  for (int gc = 0; gc < 4; ++gc) {
    f32x4 yacc[2][4];
#pragma unroll
    for (int a = 0; a < 2; ++a)
#pragma unroll
      for (int b = 0; b < 4; ++b) yacc[a][b] = f32x4{0.f, 0.f, 0.f, 0.f};

    for (int xc = 0; xc < 8; ++xc) {
      __syncthreads();  // prev phase's LDS reads done before overwrite
      *(uint4*)(xd)     = pack8(px[0], px[1]);
      *(uint4*)(xd + 8) = pack8(px[2], px[3]);
      if constexpr (WBF) {
        *(uint4*)(wd)     = pwb[0];
        *(uint4*)(wd + 8) = pwb[1];
      } else {
        *(uint4*)(wd)     = pack8(pwf[0], pwf[1]);
        *(uint4*)(wd + 8) = pack8(pwf[2], pwf[3]);
      }
      __syncthreads();
      // prefetch NEXT phase (flies during this phase's MFMA work)
      if (xc < 7) { loadX(xc + 1); loadW(gc, xc + 1); }
      else        { loadC(gc); }
      // Y-GEMM: Y[j,g] += X[j,x] * W[g,x]; wave tile 32(j) x 64(g), K-chunk 64
#pragma unroll
      for (int ks = 0; ks < 2; ++ks) {
        const int xoo = ks * 32 + h * 8;
        bf16x8 a0 = *(const bf16x8*)(sX + (wr * 32 + 0  + r) * SXW + xoo);
        bf16x8 a1 = *(const bf16x8*)(sX + (wr * 32 + 16 + r) * SXW + xoo);
#pragma unroll
        for (int bg = 0; bg < 4; ++bg) {
          bf16x8 bb = *(const bf16x8*)(sW + (wc * 64 + bg * 16 + r) * SXW + xoo);
          yacc[0][bg] = __builtin_amdgcn_mfma_f32_16x16x32_bf16(a0, bb, yacc[0][bg], 0, 0, 0);
          yacc[1][bg] = __builtin_amdgcn_mfma_f32_16x16x32_bf16(a1, bb, yacc[1][bg], 0, 0, 0);
        }
      }
    }

    // write Y chunk to sY as bf16 (D layout col=lane&15, row=(lane>>4)*4+reg)
#pragma unroll
    for (int aj = 0; aj < 2; ++aj)
#pragma unroll
      for (int bg = 0; bg < 4; ++bg)
#pragma unroll
        for (int reg = 0; reg < 4; ++reg)
          sY[(wr * 32 + aj * 16 + h * 4 + reg) * SYC + (wc * 64 + bg * 16 + r)] =
              (unsigned short)(__float_as_uint(yacc[aj][bg][reg]) >> 16);
    __syncthreads();  // all Y-MFMA reads of sX/sW done + sY writes visible
    // stage C chunk into sC (overlays sX/sW)
    *(uint4*)(cd + 0 * 32 * SYC) = pack8(pc[0], pc[1]);
    *(uint4*)(cd + 1 * 32 * SYC) = pack8(pc[2], pc[3]);
    *(uint4*)(cd + 2 * 32 * SYC) = pack8(pc[4], pc[5]);
    *(uint4*)(cd + 3 * 32 * SYC) = pack8(pc[6], pc[7]);
    __syncthreads();
    // prefetch next gc's first X/W phase (flies during Z-MFMA)
    if (gc < 3) { loadX(0); loadW(gc + 1, 0); }
    // Z-GEMM partial: Z[i,j] += C[i,g] * Y[j,g]; wave tile 32(i) x 64(j), K=128
#pragma unroll
    for (int ks = 0; ks < 4; ++ks) {
      const int go = ks * 32 + h * 8;
      bf16x8 a0 = *(const bf16x8*)(sC + (wr * 32 + 0  + r) * SYC + go);
      bf16x8 a1 = *(const bf16x8*)(sC + (wr * 32 + 16 + r) * SYC + go);
#pragma unroll
      for (int bj = 0; bj < 4; ++bj) {
        bf16x8 bb = *(const bf16x8*)(sY + (wc * 64 + bj * 16 + r) * SYC + go);
        zacc[0][bj] = __builtin_amdgcn_mfma_f32_16x16x32_bf16(a0, bb, zacc[0][bj], 0, 0, 0);
        zacc[1][bj] = __builtin_amdgcn_mfma_f32_16x16x32_bf16(a1, bb, zacc[1][bj], 0, 0, 0);
      }
    }
  }
  __syncthreads();  // all Z-MFMA LDS reads done before sZ overlay
  // dump Z to LDS fp32 (stride 132)
#pragma unroll
  for (int ai = 0; ai < 2; ++ai)
#pragma unroll
    for (int bj = 0; bj < 4; ++bj)
#pragma unroll
      for (int reg = 0; reg < 4; ++reg)
        sZ[(wr * 32 + ai * 16 + h * 4 + reg) * SZS + (wc * 64 + bj * 16 + r)] =
            zacc[ai][bj][reg];
  __syncthreads();

  // per-row lse over j (128 cols); wave handles 16 rows, 4 lanes per row
  const int row = wave * 16 + (lane >> 2);
  const int c0l = lane & 3;
  float mx = -3.4e38f;
#pragma unroll
  for (int m = 0; m < 32; ++m) mx = fmaxf(mx, sZ[row * SZS + c0l + m * 4]);
  mx = fmaxf(mx, __shfl_xor(mx, 1));
  mx = fmaxf(mx, __shfl_xor(mx, 2));
  float sum = 0.f;
#pragma unroll
  for (int m = 0; m < 32; ++m) sum += __expf(sZ[row * SZS + c0l + m * 4] - mx);
  sum += __shfl_xor(sum, 1);
  sum += __shfl_xor(sum, 2);
  float val = (c0l == 0) ? (sZ[row * SZS + row] - (__logf(sum) + mx)) : 0.f;
#pragma unroll
  for (int off = 1; off < 64; off <<= 1) val += __shfl_xor(val, off);
  if (lane == 0) sRed[wave] = val;
  __syncthreads();
  if (tid == 0) {
    float bs = 0.f;
#pragma unroll
    for (int w2 = 0; w2 < 8; ++w2) bs += sRed[w2];
    atomicAdd(out + k, bs);
  }
}

extern "C" void kernel_launch(void* const* d_in, const int* in_sizes, int n_in,
                              void* d_out, int out_size, void* d_ws, size_t ws_size,
                              hipStream_t stream) {
  const float* C = (const float*)d_in[0];
  const float* X = (const float*)d_in[1];
  const float* W = (const float*)d_in[2];
  // d_in[3] (bias) intentionally unused: j-independent bias cancels in Zdiag - lse
  float* out = (float*)d_out;

  hipLaunchKernelGGL(zero4, dim3(1), dim3(64), 0, stream, out);
  const size_t wbytes = (size_t)4 * FCn * FXn * 2;  // 2 MB bf16 W
  if (ws_size >= wbytes) {
    hipLaunchKernelGGL(wconv, dim3(1024), dim3(256), 0, stream,
                       W, (unsigned short*)d_ws);
    hipLaunchKernelGGL(infonce_main<true>, dim3(2047 * 4), dim3(512), 0, stream,
                       C, X, (const void*)d_ws, out);
  } else {
    hipLaunchKernelGGL(infonce_main<false>, dim3(2047 * 4), dim3(512), 0, stream,
                       C, X, (const void*)W, out);
  }
  hipLaunchKernelGGL(finalize4, dim3(1), dim3(64), 0, stream, out);
}

// Round 5
// 1483.115 us; speedup vs baseline: 1.7266x; 1.7266x over previous
//
#include <hip/hip_runtime.h>
#include <math.h>

// Problem constants
constexpr int Tn  = 2048;  // time
constexpr int FCn = 512;   // context feats (g)
constexpr int FXn = 512;   // encoding feats (x)
constexpr int SXW = 72;    // LDS stride (bf16 elems) for sX/sW chunks (64 + 8)
constexpr int SYC = 136;   // LDS stride (bf16 elems) for sY/sC (128 + 8)
constexpr int SZS = 132;   // LDS stride (fp32) for sZ

typedef __attribute__((ext_vector_type(8))) short  bf16x8;
typedef __attribute__((ext_vector_type(4))) float  f32x4;

// truncating fp32->bf16 pack: one v_perm_b32 per 2 elems
__device__ __forceinline__ unsigned pk2(float a, float b) {
  return __builtin_amdgcn_perm(__float_as_uint(b), __float_as_uint(a), 0x07060302u);
}
__device__ __forceinline__ uint4 pack8(float4 a, float4 b) {
  uint4 rv;
  rv.x = pk2(a.x, a.y); rv.y = pk2(a.z, a.w);
  rv.z = pk2(b.x, b.y); rv.w = pk2(b.z, b.w);
  return rv;
}

__global__ void zero4(float* out) {
  if (threadIdx.x < 4) out[threadIdx.x] = 0.0f;
}

__global__ void finalize4(float* out) {
  int k = threadIdx.x;
  if (k < 4) out[k] *= 1.0f / (128.0f * (float)(Tn - (1 << k)));
}

// prepass: W fp32 -> bf16 (trunc) into d_ws. 1M elems, 4 per thread.
__global__ void wconv(const float* __restrict__ W, unsigned short* __restrict__ Wh) {
  int i = blockIdx.x * 256 + threadIdx.x;
  float4 v = *((const float4*)W + i);
  uint2 p; p.x = pk2(v.x, v.y); p.y = pk2(v.z, v.w);
  *((uint2*)Wh + i) = p;
}

// One block per (k, t). Z[i,j] = sum_g C[i,t,g] * (sum_x W[k,g,x] X[j,t+tau,x])
// (bias dropped: j-independent bias cancels in Zdiag - lse), then row-lse and
// sum_i (Zdiag - lse) atomically accumulated into out[k].
// Register-rotate pipeline with NAMED register variables only (no arrays, no
// lambdas -- R2's lambda/array prefetch was demoted to scratch: 3.9 GB of
// scratch writes/dispatch). Loads for phase n+1 are issued right after phase
// n's LDS write, so they fly under phase n's MFMA work.
template <bool WBF>
__global__ __launch_bounds__(512, 4)
void infonce_main(const float* __restrict__ Cp, const float* __restrict__ Xp,
                  const void* __restrict__ Wp, float* __restrict__ out)
{
  // LDS: sX [128][72] | sW [128][72] | sY [128][136]  = 71680 B (2 blocks/CU)
  // sC overlays sX+sW; sZ (fp32 [128][132]) + sRed overlay everything.
  __shared__ __align__(16) unsigned char smem[71680];
  unsigned short* sX = (unsigned short*)(smem);
  unsigned short* sW = (unsigned short*)(smem + 18432);
  unsigned short* sY = (unsigned short*)(smem + 36864);
  unsigned short* sC = (unsigned short*)(smem);
  float* sZ   = (float*)(smem);
  float* sRed = (float*)(smem + 67584);

  const int tid  = threadIdx.x;
  const int lane = tid & 63;
  const int wave = tid >> 6;     // 0..7
  const int r    = lane & 15;
  const int h    = lane >> 4;    // 0..3
  const int wr   = wave >> 1;    // 0..3  (32-row group)
  const int wc   = wave & 1;     // 0..1  (64-col group)

  // bijective chunked XCD swizzle: nwg = 8188 = 8*1023 + 4 (q=1023, r=4)
  const int orig = blockIdx.x;
  const int xcd  = orig & 7;
  const int loc  = orig >> 3;
  const int wg   = (xcd < 4) ? (xcd * 1024 + loc) : (4096 + (xcd - 4) * 1023 + loc);
  const int k    = wg & 3;
  const int t    = wg >> 2;
  const int tau  = 1 << k;       // TAU = {1,2,4,8}
  if (t >= Tn - tau) return;     // uniform early-exit, before any barrier

  const float* Cb = Cp + (size_t)t * FCn;             // C[i,t,g] = Cb[i*Tn*FCn + g]
  const float* Xb = Xp + (size_t)(t + tau) * FXn;     // X[j,s,x] = Xb[j*Tn*FXn + x]

  // staging coords: 4 threads per row, 16 elems each (64-col chunk)
  const int srow = tid >> 2;
  const int scol = (tid & 3) * 16;
  const float* xs = Xb + (size_t)srow * (Tn * FXn) + scol;
  unsigned short* xd = sX + srow * SXW + scol;
  unsigned short* wd = sW + srow * SXW + scol;
  // W source (bf16 in ws, or fp32 input)
  const unsigned short* wsh = (const unsigned short*)Wp + (size_t)k * (FCn * FXn)
                              + (size_t)srow * FXn + scol;
  const float* wsf = (const float*)Wp + (size_t)k * (FCn * FXn)
                     + (size_t)srow * FXn + scol;
  // C staging coords: 16 threads per row, 8 elems each, 32 rows per rep
  const int crow0 = tid >> 4;            // 0..31
  const int ccol  = (tid & 15) * 8;
  const float* cs = Cb + (size_t)crow0 * (Tn * FCn) + ccol;
  unsigned short* cd = sC + crow0 * SYC + ccol;
  const size_t cstep = (size_t)32 * Tn * FCn;

  // prefetch registers -- all NAMED scalars/vectors (never address-taken)
  float4 px0, px1, px2, px3;           // X chunk: 16 fp32
  float4 pw0, pw1, pw2, pw3;           // W chunk fp32 path
  uint4  pb0, pb1;                     // W chunk bf16 path
  float4 pc0, pc1, pc2, pc3, pc4, pc5, pc6, pc7;  // C chunk: 32 fp32

#define LOAD_X(XC) do { \
    const float4* _p = (const float4*)(xs + (XC) * 64); \
    px0 = _p[0]; px1 = _p[1]; px2 = _p[2]; px3 = _p[3]; } while (0)
#define LOAD_W(GC, XC) do { \
    if constexpr (WBF) { \
      const uint4* _p = (const uint4*)(wsh + (size_t)((GC) * 128) * FXn + (XC) * 64); \
      pb0 = _p[0]; pb1 = _p[1]; \
    } else { \
      const float4* _p = (const float4*)(wsf + (size_t)((GC) * 128) * FXn + (XC) * 64); \
      pw0 = _p[0]; pw1 = _p[1]; pw2 = _p[2]; pw3 = _p[3]; } } while (0)
#define STORE_XW() do { \
    *(uint4*)(xd)     = pack8(px0, px1); \
    *(uint4*)(xd + 8) = pack8(px2, px3); \
    if constexpr (WBF) { *(uint4*)(wd) = pb0; *(uint4*)(wd + 8) = pb1; } \
    else { *(uint4*)(wd) = pack8(pw0, pw1); *(uint4*)(wd + 8) = pack8(pw2, pw3); } \
  } while (0)
#define MFMA_Y() do { \
    _Pragma("unroll") \
    for (int ks = 0; ks < 2; ++ks) { \
      const int xoo = ks * 32 + h * 8; \
      bf16x8 a0 = *(const bf16x8*)(sX + (wr * 32 + 0  + r) * SXW + xoo); \
      bf16x8 a1 = *(const bf16x8*)(sX + (wr * 32 + 16 + r) * SXW + xoo); \
      _Pragma("unroll") \
      for (int bg = 0; bg < 4; ++bg) { \
        bf16x8 bb = *(const bf16x8*)(sW + (wc * 64 + bg * 16 + r) * SXW + xoo); \
        yacc[0][bg] = __builtin_amdgcn_mfma_f32_16x16x32_bf16(a0, bb, yacc[0][bg], 0, 0, 0); \
        yacc[1][bg] = __builtin_amdgcn_mfma_f32_16x16x32_bf16(a1, bb, yacc[1][bg], 0, 0, 0); \
      } } } while (0)

  f32x4 zacc[2][4];
#pragma unroll
  for (int a = 0; a < 2; ++a)
#pragma unroll
    for (int b = 0; b < 4; ++b) zacc[a][b] = f32x4{0.f, 0.f, 0.f, 0.f};

  LOAD_X(0); LOAD_W(0, 0);   // prologue prefetch

  for (int gc = 0; gc < 4; ++gc) {
    f32x4 yacc[2][4];
#pragma unroll
    for (int a = 0; a < 2; ++a)
#pragma unroll
      for (int b = 0; b < 4; ++b) yacc[a][b] = f32x4{0.f, 0.f, 0.f, 0.f};

    for (int xc = 0; xc < 7; ++xc) {
      __syncthreads();  // prev phase's LDS reads done before overwrite
      STORE_XW();
      __syncthreads();
      LOAD_X(xc + 1); LOAD_W(gc, xc + 1);  // flies under this phase's MFMA
      MFMA_Y();
    }
    // xc == 7 (peeled): C prefetch takes the load slot
    __syncthreads();
    STORE_XW();
    __syncthreads();
    {
      const float4* p0 = (const float4*)(cs + 0 * cstep + gc * 128);
      const float4* p1 = (const float4*)(cs + 1 * cstep + gc * 128);
      const float4* p2 = (const float4*)(cs + 2 * cstep + gc * 128);
      const float4* p3 = (const float4*)(cs + 3 * cstep + gc * 128);
      pc0 = p0[0]; pc1 = p0[1];
      pc2 = p1[0]; pc3 = p1[1];
      pc4 = p2[0]; pc5 = p2[1];
      pc6 = p3[0]; pc7 = p3[1];
    }
    MFMA_Y();

    // write Y chunk to sY as bf16 (D layout col=lane&15, row=(lane>>4)*4+reg)
#pragma unroll
    for (int aj = 0; aj < 2; ++aj)
#pragma unroll
      for (int bg = 0; bg < 4; ++bg)
#pragma unroll
        for (int reg = 0; reg < 4; ++reg)
          sY[(wr * 32 + aj * 16 + h * 4 + reg) * SYC + (wc * 64 + bg * 16 + r)] =
              (unsigned short)(__float_as_uint(yacc[aj][bg][reg]) >> 16);
    __syncthreads();  // all Y-MFMA reads of sX/sW done + sY writes visible
    // stage C chunk into sC (overlays sX/sW)
    *(uint4*)(cd + 0 * 32 * SYC) = pack8(pc0, pc1);
    *(uint4*)(cd + 1 * 32 * SYC) = pack8(pc2, pc3);
    *(uint4*)(cd + 2 * 32 * SYC) = pack8(pc4, pc5);
    *(uint4*)(cd + 3 * 32 * SYC) = pack8(pc6, pc7);
    __syncthreads();
    // prefetch next gc's first X/W phase (flies under Z-MFMA)
    if (gc < 3) { LOAD_X(0); LOAD_W(gc + 1, 0); }
    // Z-GEMM partial: Z[i,j] += C[i,g] * Y[j,g]; wave tile 32(i) x 64(j), K=128
#pragma unroll
    for (int ks = 0; ks < 4; ++ks) {
      const int go = ks * 32 + h * 8;
      bf16x8 a0 = *(const bf16x8*)(sC + (wr * 32 + 0  + r) * SYC + go);
      bf16x8 a1 = *(const bf16x8*)(sC + (wr * 32 + 16 + r) * SYC + go);
#pragma unroll
      for (int bj = 0; bj < 4; ++bj) {
        bf16x8 bb = *(const bf16x8*)(sY + (wc * 64 + bj * 16 + r) * SYC + go);
        zacc[0][bj] = __builtin_amdgcn_mfma_f32_16x16x32_bf16(a0, bb, zacc[0][bj], 0, 0, 0);
        zacc[1][bj] = __builtin_amdgcn_mfma_f32_16x16x32_bf16(a1, bb, zacc[1][bj], 0, 0, 0);
      }
    }
  }
  __syncthreads();  // all Z-MFMA LDS reads done before sZ overlay
  // dump Z to LDS fp32 (stride 132)
#pragma unroll
  for (int ai = 0; ai < 2; ++ai)
#pragma unroll
    for (int bj = 0; bj < 4; ++bj)
#pragma unroll
      for (int reg = 0; reg < 4; ++reg)
        sZ[(wr * 32 + ai * 16 + h * 4 + reg) * SZS + (wc * 64 + bj * 16 + r)] =
            zacc[ai][bj][reg];
  __syncthreads();

  // per-row lse over j (128 cols); wave handles 16 rows, 4 lanes per row
  const int row = wave * 16 + (lane >> 2);
  const int c0l = lane & 3;
  float mx = -3.4e38f;
#pragma unroll
  for (int m = 0; m < 32; ++m) mx = fmaxf(mx, sZ[row * SZS + c0l + m * 4]);
  mx = fmaxf(mx, __shfl_xor(mx, 1));
  mx = fmaxf(mx, __shfl_xor(mx, 2));
  float sum = 0.f;
#pragma unroll
  for (int m = 0; m < 32; ++m) sum += __expf(sZ[row * SZS + c0l + m * 4] - mx);
  sum += __shfl_xor(sum, 1);
  sum += __shfl_xor(sum, 2);
  float val = (c0l == 0) ? (sZ[row * SZS + row] - (__logf(sum) + mx)) : 0.f;
#pragma unroll
  for (int off = 1; off < 64; off <<= 1) val += __shfl_xor(val, off);
  if (lane == 0) sRed[wave] = val;
  __syncthreads();
  if (tid == 0) {
    float bs = 0.f;
#pragma unroll
    for (int w2 = 0; w2 < 8; ++w2) bs += sRed[w2];
    atomicAdd(out + k, bs);
  }
#undef LOAD_X
#undef LOAD_W
#undef STORE_XW
#undef MFMA_Y
}

extern "C" void kernel_launch(void* const* d_in, const int* in_sizes, int n_in,
                              void* d_out, int out_size, void* d_ws, size_t ws_size,
                              hipStream_t stream) {
  const float* C = (const float*)d_in[0];
  const float* X = (const float*)d_in[1];
  const float* W = (const float*)d_in[2];
  // d_in[3] (bias) intentionally unused: j-independent bias cancels in Zdiag - lse
  float* out = (float*)d_out;

  hipLaunchKernelGGL(zero4, dim3(1), dim3(64), 0, stream, out);
  const size_t wbytes = (size_t)4 * FCn * FXn * 2;  // 2 MB bf16 W
  if (ws_size >= wbytes) {
    hipLaunchKernelGGL(wconv, dim3(1024), dim3(256), 0, stream,
                       W, (unsigned short*)d_ws);
    hipLaunchKernelGGL(infonce_main<true>, dim3(2047 * 4), dim3(512), 0, stream,
                       C, X, (const void*)d_ws, out);
  } else {
    hipLaunchKernelGGL(infonce_main<false>, dim3(2047 * 4), dim3(512), 0, stream,
                       C, X, (const void*)W, out);
  }
  hipLaunchKernelGGL(finalize4, dim3(1), dim3(64), 0, stream, out);
}

// Round 6
// 1454.821 us; speedup vs baseline: 1.7602x; 1.0194x over previous
//
#include <hip/hip_runtime.h>
#include <math.h>

// Problem constants
constexpr int Tn  = 2048;  // time
constexpr int FCn = 512;   // context feats (g)
constexpr int FXn = 512;   // encoding feats (x)
constexpr int SXW = 72;    // LDS stride (bf16 elems) for sX/sW chunks (64 + 8)
constexpr int SYC = 136;   // LDS stride (bf16 elems) for sY/sC (128 + 8)
constexpr int SZS = 132;   // LDS stride (fp32) for sZ

typedef __attribute__((ext_vector_type(8))) short  bf16x8;
typedef __attribute__((ext_vector_type(4))) float  f32x4;

// truncating fp32->bf16 pack: one v_perm_b32 per 2 elems
__device__ __forceinline__ unsigned pk2(float a, float b) {
  return __builtin_amdgcn_perm(__float_as_uint(b), __float_as_uint(a), 0x07060302u);
}
__device__ __forceinline__ uint4 pack8(float4 a, float4 b) {
  uint4 rv;
  rv.x = pk2(a.x, a.y); rv.y = pk2(a.z, a.w);
  rv.z = pk2(b.x, b.y); rv.w = pk2(b.z, b.w);
  return rv;
}

__global__ void zero4(float* out) {
  if (threadIdx.x < 4) out[threadIdx.x] = 0.0f;
}

__global__ void finalize4(float* out) {
  int k = threadIdx.x;
  if (k < 4) out[k] *= 1.0f / (128.0f * (float)(Tn - (1 << k)));
}

// fp32 -> bf16 (trunc, matches pack8 numerics) converter, 4 elems/thread
__global__ void tobf16(const float* __restrict__ s, unsigned short* __restrict__ d) {
  int i = blockIdx.x * 256 + threadIdx.x;
  float4 v = ((const float4*)s)[i];
  uint2 p; p.x = pk2(v.x, v.y); p.y = pk2(v.z, v.w);
  ((uint2*)d)[i] = p;
}

// ---------------- full-bf16 main kernel (Xb, Wb bf16; C bf16 or fp32-direct) ---
// One block per (k, t). Z[i,j] = sum_g C[i,t,g] * (sum_x W[k,g,x] X[j,t+tau,x])
// (bias dropped: j-independent bias cancels in Zdiag - lse).
// X/W staged to LDS (uint4 passthrough, one-phase-ahead named-reg prefetch);
// C consumed DIRECTLY from global as Z-GEMM A-fragments (no sC stage, no pc regs).
template <bool CBF>
__global__ __launch_bounds__(512, 4)
void infonce_bf16(const void* __restrict__ Cany, const unsigned short* __restrict__ Xb,
                  const unsigned short* __restrict__ Wb, float* __restrict__ out)
{
  // LDS: sX [128][72] | sW [128][72] | sY [128][136] = 71680 B (2 blocks/CU)
  // sZ (fp32 [128][132] = 67584 B) + sRed overlay everything after last MFMA.
  __shared__ __align__(16) unsigned char smem[71680];
  unsigned short* sX = (unsigned short*)(smem);
  unsigned short* sW = (unsigned short*)(smem + 18432);
  unsigned short* sY = (unsigned short*)(smem + 36864);
  float* sZ   = (float*)(smem);
  float* sRed = (float*)(smem + 67584);

  const int tid  = threadIdx.x;
  const int lane = tid & 63;
  const int wave = tid >> 6;     // 0..7
  const int r    = lane & 15;
  const int h    = lane >> 4;    // 0..3
  const int wr   = wave >> 1;    // 0..3  (32-row group)
  const int wc   = wave & 1;     // 0..1  (64-col group)

  // bijective chunked XCD swizzle: nwg = 8188 = 8*1023 + 4 (q=1023, r=4)
  const int orig = blockIdx.x;
  const int xcd  = orig & 7;
  const int loc  = orig >> 3;
  const int wg   = (xcd < 4) ? (xcd * 1024 + loc) : (4096 + (xcd - 4) * 1023 + loc);
  const int k    = wg & 3;
  const int t    = wg >> 2;
  const int tau  = 1 << k;       // TAU = {1,2,4,8}
  if (t >= Tn - tau) return;     // uniform early-exit, before any barrier

  // staging coords: 4 threads per row, 16 elems each (64-col chunk)
  const int srow = tid >> 2;
  const int scol = (tid & 3) * 16;
  const unsigned short* xs = Xb + (size_t)srow * (Tn * FXn)
                             + (size_t)(t + tau) * FXn + scol;
  const unsigned short* ws = Wb + (size_t)k * (FCn * FXn) + (size_t)srow * FXn + scol;
  unsigned short* xd = sX + srow * SXW + scol;
  unsigned short* wd = sW + srow * SXW + scol;

  // C rows for Z-GEMM A-fragments (direct from global)
  const unsigned short* c0h = nullptr; const unsigned short* c1h = nullptr;
  const float*          c0f = nullptr; const float*          c1f = nullptr;
  if constexpr (CBF) {
    c0h = (const unsigned short*)Cany + (size_t)(wr * 32 + r) * (Tn * FCn)
          + (size_t)t * FCn;
    c1h = c0h + (size_t)16 * (Tn * FCn);
  } else {
    c0f = (const float*)Cany + (size_t)(wr * 32 + r) * (Tn * FCn) + (size_t)t * FCn;
    c1f = c0f + (size_t)16 * (Tn * FCn);
  }

  // prefetch registers -- NAMED only (never address-taken)
  uint4 px0, px1, pw0, pw1;

#define LOAD_X(XC) do { \
    const uint4* _p = (const uint4*)(xs + (XC) * 64); \
    px0 = _p[0]; px1 = _p[1]; } while (0)
#define LOAD_W(GC, XC) do { \
    const uint4* _p = (const uint4*)(ws + (size_t)((GC) * 128) * FXn + (XC) * 64); \
    pw0 = _p[0]; pw1 = _p[1]; } while (0)
#define STORE_XW() do { \
    *(uint4*)(xd) = px0; *(uint4*)(xd + 8) = px1; \
    *(uint4*)(wd) = pw0; *(uint4*)(wd + 8) = pw1; } while (0)
#define MFMA_Y() do { \
    _Pragma("unroll") \
    for (int ks = 0; ks < 2; ++ks) { \
      const int xoo = ks * 32 + h * 8; \
      bf16x8 a0 = *(const bf16x8*)(sX + (wr * 32 + 0  + r) * SXW + xoo); \
      bf16x8 a1 = *(const bf16x8*)(sX + (wr * 32 + 16 + r) * SXW + xoo); \
      _Pragma("unroll") \
      for (int bg = 0; bg < 4; ++bg) { \
        bf16x8 bb = *(const bf16x8*)(sW + (wc * 64 + bg * 16 + r) * SXW + xoo); \
        yacc[0][bg] = __builtin_amdgcn_mfma_f32_16x16x32_bf16(a0, bb, yacc[0][bg], 0, 0, 0); \
        yacc[1][bg] = __builtin_amdgcn_mfma_f32_16x16x32_bf16(a1, bb, yacc[1][bg], 0, 0, 0); \
      } } } while (0)

  f32x4 zacc[2][4];
#pragma unroll
  for (int a = 0; a < 2; ++a)
#pragma unroll
    for (int b = 0; b < 4; ++b) zacc[a][b] = f32x4{0.f, 0.f, 0.f, 0.f};

  LOAD_X(0); LOAD_W(0, 0);   // prologue prefetch

  for (int gc = 0; gc < 4; ++gc) {
    f32x4 yacc[2][4];
#pragma unroll
    for (int a = 0; a < 2; ++a)
#pragma unroll
      for (int b = 0; b < 4; ++b) yacc[a][b] = f32x4{0.f, 0.f, 0.f, 0.f};

#pragma unroll 1
    for (int xc = 0; xc < 8; ++xc) {
      __syncthreads();  // prev phase's LDS reads done before overwrite
      STORE_XW();
      __syncthreads();
      // prefetch next phase (flies under this phase's MFMA; at xc==7 it also
      // flies under the Y-write + Z-GEMM phases -- extra distance)
      if (xc < 7)      { LOAD_X(xc + 1); LOAD_W(gc, xc + 1); }
      else if (gc < 3) { LOAD_X(0);      LOAD_W(gc + 1, 0); }
      MFMA_Y();
    }

    // write Y chunk to sY as bf16 (D layout col=lane&15, row=(lane>>4)*4+reg)
#pragma unroll
    for (int aj = 0; aj < 2; ++aj)
#pragma unroll
      for (int bg = 0; bg < 4; ++bg)
#pragma unroll
        for (int reg = 0; reg < 4; ++reg)
          sY[(wr * 32 + aj * 16 + h * 4 + reg) * SYC + (wc * 64 + bg * 16 + r)] =
              (unsigned short)(__float_as_uint(yacc[aj][bg][reg]) >> 16);
    __syncthreads();  // sY writes visible to all waves

    // Z-GEMM partial: Z[i,j] += C[i,g] * Y[j,g]; A-frags direct from global C
#pragma unroll
    for (int ks = 0; ks < 4; ++ks) {
      const int go = ks * 32 + h * 8;
      bf16x8 a0, a1;
      if constexpr (CBF) {
        a0 = *(const bf16x8*)(c0h + gc * 128 + go);
        a1 = *(const bf16x8*)(c1h + gc * 128 + go);
      } else {
        float4 ca = *(const float4*)(c0f + gc * 128 + go);
        float4 cb = *(const float4*)(c0f + gc * 128 + go + 4);
        float4 cc = *(const float4*)(c1f + gc * 128 + go);
        float4 cd = *(const float4*)(c1f + gc * 128 + go + 4);
        a0 = __builtin_bit_cast(bf16x8, pack8(ca, cb));
        a1 = __builtin_bit_cast(bf16x8, pack8(cc, cd));
      }
#pragma unroll
      for (int bj = 0; bj < 4; ++bj) {
        bf16x8 bb = *(const bf16x8*)(sY + (wc * 64 + bj * 16 + r) * SYC + go);
        zacc[0][bj] = __builtin_amdgcn_mfma_f32_16x16x32_bf16(a0, bb, zacc[0][bj], 0, 0, 0);
        zacc[1][bj] = __builtin_amdgcn_mfma_f32_16x16x32_bf16(a1, bb, zacc[1][bj], 0, 0, 0);
      }
    }
  }
  __syncthreads();  // all Z-MFMA sY reads done before sZ overlay
  // dump Z to LDS fp32 (stride 132)
#pragma unroll
  for (int ai = 0; ai < 2; ++ai)
#pragma unroll
    for (int bj = 0; bj < 4; ++bj)
#pragma unroll
      for (int reg = 0; reg < 4; ++reg)
        sZ[(wr * 32 + ai * 16 + h * 4 + reg) * SZS + (wc * 64 + bj * 16 + r)] =
            zacc[ai][bj][reg];
  __syncthreads();

  // per-row lse over j (128 cols); wave handles 16 rows, 4 lanes per row
  const int row = wave * 16 + (lane >> 2);
  const int c0l = lane & 3;
  float mx = -3.4e38f;
#pragma unroll
  for (int m = 0; m < 32; ++m) mx = fmaxf(mx, sZ[row * SZS + c0l + m * 4]);
  mx = fmaxf(mx, __shfl_xor(mx, 1));
  mx = fmaxf(mx, __shfl_xor(mx, 2));
  float sum = 0.f;
#pragma unroll
  for (int m = 0; m < 32; ++m) sum += __expf(sZ[row * SZS + c0l + m * 4] - mx);
  sum += __shfl_xor(sum, 1);
  sum += __shfl_xor(sum, 2);
  float val = (c0l == 0) ? (sZ[row * SZS + row] - (__logf(sum) + mx)) : 0.f;
#pragma unroll
  for (int off = 1; off < 64; off <<= 1) val += __shfl_xor(val, off);
  if (lane == 0) sRed[wave] = val;
  __syncthreads();
  if (tid == 0) {
    float bs = 0.f;
#pragma unroll
    for (int w2 = 0; w2 < 8; ++w2) bs += sRed[w2];
    atomicAdd(out + k, bs);
  }
#undef LOAD_X
#undef LOAD_W
#undef STORE_XW
#undef MFMA_Y
}

// ---------------- R5 fallback kernel (proven 1483 us) --------------------------
template <bool WBF>
__global__ __launch_bounds__(512, 4)
void infonce_main(const float* __restrict__ Cp, const float* __restrict__ Xp,
                  const void* __restrict__ Wp, float* __restrict__ out)
{
  __shared__ __align__(16) unsigned char smem[71680];
  unsigned short* sX = (unsigned short*)(smem);
  unsigned short* sW = (unsigned short*)(smem + 18432);
  unsigned short* sY = (unsigned short*)(smem + 36864);
  unsigned short* sC = (unsigned short*)(smem);
  float* sZ   = (float*)(smem);
  float* sRed = (float*)(smem + 67584);

  const int tid  = threadIdx.x;
  const int lane = tid & 63;
  const int wave = tid >> 6;
  const int r    = lane & 15;
  const int h    = lane >> 4;
  const int wr   = wave >> 1;
  const int wc   = wave & 1;

  const int orig = blockIdx.x;
  const int xcd  = orig & 7;
  const int loc  = orig >> 3;
  const int wg   = (xcd < 4) ? (xcd * 1024 + loc) : (4096 + (xcd - 4) * 1023 + loc);
  const int k    = wg & 3;
  const int t    = wg >> 2;
  const int tau  = 1 << k;
  if (t >= Tn - tau) return;

  const float* Cb = Cp + (size_t)t * FCn;
  const float* Xb = Xp + (size_t)(t + tau) * FXn;

  const int srow = tid >> 2;
  const int scol = (tid & 3) * 16;
  const float* xs = Xb + (size_t)srow * (Tn * FXn) + scol;
  unsigned short* xd = sX + srow * SXW + scol;
  unsigned short* wd = sW + srow * SXW + scol;
  const unsigned short* wsh = (const unsigned short*)Wp + (size_t)k * (FCn * FXn)
                              + (size_t)srow * FXn + scol;
  const float* wsf = (const float*)Wp + (size_t)k * (FCn * FXn)
                     + (size_t)srow * FXn + scol;
  const int crow0 = tid >> 4;
  const int ccol  = (tid & 15) * 8;
  const float* cs = Cb + (size_t)crow0 * (Tn * FCn) + ccol;
  unsigned short* cd = sC + crow0 * SYC + ccol;
  const size_t cstep = (size_t)32 * Tn * FCn;

  float4 px0, px1, px2, px3;
  float4 pw0, pw1, pw2, pw3;
  uint4  pb0, pb1;
  float4 pc0, pc1, pc2, pc3, pc4, pc5, pc6, pc7;

#define LOAD_X(XC) do { \
    const float4* _p = (const float4*)(xs + (XC) * 64); \
    px0 = _p[0]; px1 = _p[1]; px2 = _p[2]; px3 = _p[3]; } while (0)
#define LOAD_W(GC, XC) do { \
    if constexpr (WBF) { \
      const uint4* _p = (const uint4*)(wsh + (size_t)((GC) * 128) * FXn + (XC) * 64); \
      pb0 = _p[0]; pb1 = _p[1]; \
    } else { \
      const float4* _p = (const float4*)(wsf + (size_t)((GC) * 128) * FXn + (XC) * 64); \
      pw0 = _p[0]; pw1 = _p[1]; pw2 = _p[2]; pw3 = _p[3]; } } while (0)
#define STORE_XW() do { \
    *(uint4*)(xd)     = pack8(px0, px1); \
    *(uint4*)(xd + 8) = pack8(px2, px3); \
    if constexpr (WBF) { *(uint4*)(wd) = pb0; *(uint4*)(wd + 8) = pb1; } \
    else { *(uint4*)(wd) = pack8(pw0, pw1); *(uint4*)(wd + 8) = pack8(pw2, pw3); } \
  } while (0)
#define MFMA_Y() do { \
    _Pragma("unroll") \
    for (int ks = 0; ks < 2; ++ks) { \
      const int xoo = ks * 32 + h * 8; \
      bf16x8 a0 = *(const bf16x8*)(sX + (wr * 32 + 0  + r) * SXW + xoo); \
      bf16x8 a1 = *(const bf16x8*)(sX + (wr * 32 + 16 + r) * SXW + xoo); \
      _Pragma("unroll") \
      for (int bg = 0; bg < 4; ++bg) { \
        bf16x8 bb = *(const bf16x8*)(sW + (wc * 64 + bg * 16 + r) * SXW + xoo); \
        yacc[0][bg] = __builtin_amdgcn_mfma_f32_16x16x32_bf16(a0, bb, yacc[0][bg], 0, 0, 0); \
        yacc[1][bg] = __builtin_amdgcn_mfma_f32_16x16x32_bf16(a1, bb, yacc[1][bg], 0, 0, 0); \
      } } } while (0)

  f32x4 zacc[2][4];
#pragma unroll
  for (int a = 0; a < 2; ++a)
#pragma unroll
    for (int b = 0; b < 4; ++b) zacc[a][b] = f32x4{0.f, 0.f, 0.f, 0.f};

  LOAD_X(0); LOAD_W(0, 0);

  for (int gc = 0; gc < 4; ++gc) {
    f32x4 yacc[2][4];
#pragma unroll
    for (int a = 0; a < 2; ++a)
#pragma unroll
      for (int b = 0; b < 4; ++b) yacc[a][b] = f32x4{0.f, 0.f, 0.f, 0.f};

    for (int xc = 0; xc < 7; ++xc) {
      __syncthreads();
      STORE_XW();
      __syncthreads();
      LOAD_X(xc + 1); LOAD_W(gc, xc + 1);
      MFMA_Y();
    }
    __syncthreads();
    STORE_XW();
    __syncthreads();
    {
      const float4* p0 = (const float4*)(cs + 0 * cstep + gc * 128);
      const float4* p1 = (const float4*)(cs + 1 * cstep + gc * 128);
      const float4* p2 = (const float4*)(cs + 2 * cstep + gc * 128);
      const float4* p3 = (const float4*)(cs + 3 * cstep + gc * 128);
      pc0 = p0[0]; pc1 = p0[1];
      pc2 = p1[0]; pc3 = p1[1];
      pc4 = p2[0]; pc5 = p2[1];
      pc6 = p3[0]; pc7 = p3[1];
    }
    MFMA_Y();

#pragma unroll
    for (int aj = 0; aj < 2; ++aj)
#pragma unroll
      for (int bg = 0; bg < 4; ++bg)
#pragma unroll
        for (int reg = 0; reg < 4; ++reg)
          sY[(wr * 32 + aj * 16 + h * 4 + reg) * SYC + (wc * 64 + bg * 16 + r)] =
              (unsigned short)(__float_as_uint(yacc[aj][bg][reg]) >> 16);
    __syncthreads();
    *(uint4*)(cd + 0 * 32 * SYC) = pack8(pc0, pc1);
    *(uint4*)(cd + 1 * 32 * SYC) = pack8(pc2, pc3);
    *(uint4*)(cd + 2 * 32 * SYC) = pack8(pc4, pc5);
    *(uint4*)(cd + 3 * 32 * SYC) = pack8(pc6, pc7);
    __syncthreads();
    if (gc < 3) { LOAD_X(0); LOAD_W(gc + 1, 0); }
#pragma unroll
    for (int ks = 0; ks < 4; ++ks) {
      const int go = ks * 32 + h * 8;
      bf16x8 a0 = *(const bf16x8*)(sC + (wr * 32 + 0  + r) * SYC + go);
      bf16x8 a1 = *(const bf16x8*)(sC + (wr * 32 + 16 + r) * SYC + go);
#pragma unroll
      for (int bj = 0; bj < 4; ++bj) {
        bf16x8 bb = *(const bf16x8*)(sY + (wc * 64 + bj * 16 + r) * SYC + go);
        zacc[0][bj] = __builtin_amdgcn_mfma_f32_16x16x32_bf16(a0, bb, zacc[0][bj], 0, 0, 0);
        zacc[1][bj] = __builtin_amdgcn_mfma_f32_16x16x32_bf16(a1, bb, zacc[1][bj], 0, 0, 0);
      }
    }
  }
  __syncthreads();
#pragma unroll
  for (int ai = 0; ai < 2; ++ai)
#pragma unroll
    for (int bj = 0; bj < 4; ++bj)
#pragma unroll
      for (int reg = 0; reg < 4; ++reg)
        sZ[(wr * 32 + ai * 16 + h * 4 + reg) * SZS + (wc * 64 + bj * 16 + r)] =
            zacc[ai][bj][reg];
  __syncthreads();

  const int row = wave * 16 + (lane >> 2);
  const int c0l = lane & 3;
  float mx = -3.4e38f;
#pragma unroll
  for (int m = 0; m < 32; ++m) mx = fmaxf(mx, sZ[row * SZS + c0l + m * 4]);
  mx = fmaxf(mx, __shfl_xor(mx, 1));
  mx = fmaxf(mx, __shfl_xor(mx, 2));
  float sum = 0.f;
#pragma unroll
  for (int m = 0; m < 32; ++m) sum += __expf(sZ[row * SZS + c0l + m * 4] - mx);
  sum += __shfl_xor(sum, 1);
  sum += __shfl_xor(sum, 2);
  float val = (c0l == 0) ? (sZ[row * SZS + row] - (__logf(sum) + mx)) : 0.f;
#pragma unroll
  for (int off = 1; off < 64; off <<= 1) val += __shfl_xor(val, off);
  if (lane == 0) sRed[wave] = val;
  __syncthreads();
  if (tid == 0) {
    float bs = 0.f;
#pragma unroll
    for (int w2 = 0; w2 < 8; ++w2) bs += sRed[w2];
    atomicAdd(out + k, bs);
  }
#undef LOAD_X
#undef LOAD_W
#undef STORE_XW
#undef MFMA_Y
}

extern "C" void kernel_launch(void* const* d_in, const int* in_sizes, int n_in,
                              void* d_out, int out_size, void* d_ws, size_t ws_size,
                              hipStream_t stream) {
  const float* C = (const float*)d_in[0];
  const float* X = (const float*)d_in[1];
  const float* W = (const float*)d_in[2];
  // d_in[3] (bias) intentionally unused: j-independent bias cancels in Zdiag - lse
  float* out = (float*)d_out;

  const size_t NX = (size_t)128 * Tn * FXn;        // 134,217,728 elems (X and C)
  const size_t NW = (size_t)4 * FCn * FXn;         // 1,048,576 elems
  const size_t WS_W    = NW * 2;                   // 2 MB
  const size_t WS_MID  = WS_W + NX * 2;            // + Xbf = 270,532,608
  const size_t WS_FULL = WS_MID + NX * 2;          // + Cbf = 538,968,064

  hipLaunchKernelGGL(zero4, dim3(1), dim3(64), 0, stream, out);

  if (ws_size >= WS_MID) {
    unsigned short* Wbf = (unsigned short*)d_ws;
    unsigned short* Xbf = (unsigned short*)((char*)d_ws + WS_W);
    hipLaunchKernelGGL(tobf16, dim3((unsigned)(NW / 1024)), dim3(256), 0, stream, W, Wbf);
    hipLaunchKernelGGL(tobf16, dim3((unsigned)(NX / 1024)), dim3(256), 0, stream, X, Xbf);
    if (ws_size >= WS_FULL) {
      unsigned short* Cbf = (unsigned short*)((char*)d_ws + WS_MID);
      hipLaunchKernelGGL(tobf16, dim3((unsigned)(NX / 1024)), dim3(256), 0, stream, C, Cbf);
      hipLaunchKernelGGL(infonce_bf16<true>, dim3(2047 * 4), dim3(512), 0, stream,
                         (const void*)Cbf, Xbf, Wbf, out);
    } else {
      hipLaunchKernelGGL(infonce_bf16<false>, dim3(2047 * 4), dim3(512), 0, stream,
                         (const void*)C, Xbf, Wbf, out);
    }
  } else if (ws_size >= WS_W) {
    hipLaunchKernelGGL(tobf16, dim3((unsigned)(NW / 1024)), dim3(256), 0, stream,
                       W, (unsigned short*)d_ws);
    hipLaunchKernelGGL(infonce_main<true>, dim3(2047 * 4), dim3(512), 0, stream,
                       C, X, (const void*)d_ws, out);
  } else {
    hipLaunchKernelGGL(infonce_main<false>, dim3(2047 * 4), dim3(512), 0, stream,
                       C, X, (const void*)W, out);
  }
  hipLaunchKernelGGL(finalize4, dim3(1), dim3(64), 0, stream, out);
}

// Round 7
// 1363.712 us; speedup vs baseline: 1.8778x; 1.0668x over previous
//
#include <hip/hip_runtime.h>
#include <math.h>

// Problem constants
constexpr int Tn  = 2048;  // time
constexpr int FCn = 512;   // context feats (g)
constexpr int FXn = 512;   // encoding feats (x)
constexpr int SXW = 72;    // (fallback kernel) LDS stride bf16 for sX/sW
constexpr int SYC = 136;   // (fallback kernel) LDS stride bf16 for sY/sC
constexpr int SZS = 132;   // LDS stride (fp32) for sZ

typedef __attribute__((ext_vector_type(8))) short  bf16x8;
typedef __attribute__((ext_vector_type(4))) float  f32x4;

// truncating fp32->bf16 pack: one v_perm_b32 per 2 elems
__device__ __forceinline__ unsigned pk2(float a, float b) {
  return __builtin_amdgcn_perm(__float_as_uint(b), __float_as_uint(a), 0x07060302u);
}
__device__ __forceinline__ uint4 pack8(float4 a, float4 b) {
  uint4 rv;
  rv.x = pk2(a.x, a.y); rv.y = pk2(a.z, a.w);
  rv.z = pk2(b.x, b.y); rv.w = pk2(b.z, b.w);
  return rv;
}

// async global->LDS 16B copy (dest = wave-uniform base + lane*16)
__device__ __forceinline__ void gll16(const unsigned short* g, void* lds) {
  __builtin_amdgcn_global_load_lds(
      (const __attribute__((address_space(1))) unsigned int*)g,
      (__attribute__((address_space(3))) unsigned int*)lds, 16, 0, 0);
}

__global__ void zero4(float* out) {
  if (threadIdx.x < 4) out[threadIdx.x] = 0.0f;
}

__global__ void finalize4(float* out) {
  int k = threadIdx.x;
  if (k < 4) out[k] *= 1.0f / (128.0f * (float)(Tn - (1 << k)));
}

// fp32 -> bf16 (trunc) converter, 4 elems/thread
__global__ void tobf16(const float* __restrict__ s, unsigned short* __restrict__ d) {
  int i = blockIdx.x * 256 + threadIdx.x;
  float4 v = ((const float4*)s)[i];
  uint2 p; p.x = pk2(v.x, v.y); p.y = pk2(v.z, v.w);
  ((uint2*)d)[i] = p;
}

// ---------------- v7 main kernel ----------------------------------------------
// One 256-thread (4-wave) block per (k,t). Wave tiles: Y 64(j)x128(g),
// Z 64(i)x64(j). X/W staged via global_load_lds from bf16 ws copies with
// XOR-16B-granule swizzle (pre-swizzled SOURCE + swizzled ds_read: both-sides).
// C consumed fp32-direct from global (ws budget < full-C tier).
// LDS map per gc: [sX 16K | sW 32K] -> overlay sY [128][264]b16 (67.6K);
// sZ fp32 [128][132] overlays all at the end. sRed at 67584.
__global__ __launch_bounds__(256, 2)
void infonce_v7(const float* __restrict__ Cp, const unsigned short* __restrict__ Xb,
                const unsigned short* __restrict__ Wb, float* __restrict__ out)
{
  __shared__ __align__(16) unsigned char smem[67648];
  char* sm   = (char*)smem;
  char* sWc  = sm + 16384;
  float* sZ  = (float*)sm;
  float* sRed = (float*)(sm + 67584);

  const int tid  = threadIdx.x;
  const int lane = tid & 63;
  const int wave = tid >> 6;     // 0..3
  const int r    = lane & 15;
  const int h    = lane >> 4;    // 0..3
  const int jw   = wave >> 1;    // Y: j-half (0..1)
  const int gw   = wave & 1;     // Y: g-half (0..1)
  const int iw   = wave >> 1;    // Z: i-half
  const int jw2  = wave & 1;     // Z: j-half

  // bijective chunked XCD swizzle: nwg = 8188 = 8*1023 + 4
  const int orig = blockIdx.x;
  const int xcd  = orig & 7;
  const int loc  = orig >> 3;
  const int wg   = (xcd < 4) ? (xcd * 1024 + loc) : (4096 + (xcd - 4) * 1023 + loc);
  const int k    = wg & 3;
  const int t    = wg >> 2;
  const int tau  = 1 << k;       // TAU = {1,2,4,8}
  if (t >= Tn - tau) return;     // uniform early-exit, before any barrier
  const int s = t + tau;

  // staging lane constants (source pre-swizzle: granule colg = (l&7)^(l>>3))
  const int colg = (lane & 7) ^ (lane >> 3);
  const unsigned short* xlane = Xb + (size_t)(wave * 32 + (lane >> 3)) * (Tn * FXn)
                                + (size_t)s * FXn + colg * 8;
  const unsigned short* wlane = Wb + (size_t)k * (FCn * FXn)
                                + (size_t)(wave * 64 + (lane >> 3)) * FXn + colg * 8;
  char* xdst = sm  + wave * 4096;   // + i*1024 (wave-uniform)
  char* wdst = sWc + wave * 8192;   // + i*1024

  // C row pointers for Z A-frags (fp32 direct; truncated to bf16 in-regs)
  const float* cr0 = Cp + (size_t)(iw * 64 +  0 + r) * (Tn * FCn) + (size_t)t * FCn;
  const float* cr1 = Cp + (size_t)(iw * 64 + 16 + r) * (Tn * FCn) + (size_t)t * FCn;
  const float* cr2 = Cp + (size_t)(iw * 64 + 32 + r) * (Tn * FCn) + (size_t)t * FCn;
  const float* cr3 = Cp + (size_t)(iw * 64 + 48 + r) * (Tn * FCn) + (size_t)t * FCn;

  f32x4 zacc[4][4];
#pragma unroll
  for (int a = 0; a < 4; ++a)
#pragma unroll
    for (int b = 0; b < 4; ++b) zacc[a][b] = f32x4{0.f, 0.f, 0.f, 0.f};

#pragma unroll 1
  for (int gc = 0; gc < 2; ++gc) {
    f32x4 yacc[4][8];
#pragma unroll
    for (int a = 0; a < 4; ++a)
#pragma unroll
      for (int b = 0; b < 8; ++b) yacc[a][b] = f32x4{0.f, 0.f, 0.f, 0.f};

#pragma unroll 1
    for (int xc = 0; xc < 8; ++xc) {
      __syncthreads();  // prior reads of this LDS region done
      // stage X chunk 128x64 (16KB) + W chunk 256x64 (32KB), async
#pragma unroll
      for (int i = 0; i < 4; ++i)
        gll16(xlane + (size_t)(i * 8) * (Tn * FXn) + xc * 64, xdst + i * 1024);
#pragma unroll
      for (int i = 0; i < 8; ++i)
        gll16(wlane + (size_t)(gc * 256 + i * 8) * FXn + xc * 64, wdst + i * 1024);
      __syncthreads();  // vmcnt(0) drain: staged data visible
      // Y-GEMM: wave tile 64(j) x 128(g), K-chunk 64
#pragma unroll
      for (int ks = 0; ks < 2; ++ks) {
        const int cbx = (ks * 64 + h * 16) ^ ((r & 7) << 4);  // swizzled byte col
        bf16x8 ax[4], bw[8];
#pragma unroll
        for (int bm = 0; bm < 4; ++bm)
          ax[bm] = *(const bf16x8*)(sm + (jw * 64 + bm * 16 + r) * 128 + cbx);
#pragma unroll
        for (int bn = 0; bn < 8; ++bn)
          bw[bn] = *(const bf16x8*)(sWc + (gw * 128 + bn * 16 + r) * 128 + cbx);
#pragma unroll
        for (int bm = 0; bm < 4; ++bm)
#pragma unroll
          for (int bn = 0; bn < 8; ++bn)
            yacc[bm][bn] = __builtin_amdgcn_mfma_f32_16x16x32_bf16(
                ax[bm], bw[bn], yacc[bm][bn], 0, 0, 0);
      }
    }
    __syncthreads();  // all Y-MFMA LDS reads done before sY overlay write
    // write Y (64x128 per wave) to sY[128][264] bf16, row stride 528 B
#pragma unroll
    for (int bm = 0; bm < 4; ++bm)
#pragma unroll
      for (int bn = 0; bn < 8; ++bn)
#pragma unroll
        for (int reg = 0; reg < 4; ++reg) {
          const int row = jw * 64 + bm * 16 + h * 4 + reg;
          const int col = gw * 128 + bn * 16 + r;
          *(unsigned short*)(sm + row * 528 + col * 2) =
              (unsigned short)(__float_as_uint(yacc[bm][bn][reg]) >> 16);
        }
    __syncthreads();  // sY visible
    // Z-GEMM: wave tile 64(i) x 64(j), K = 256 (this gc's g-chunk)
#pragma unroll 2
    for (int ks2 = 0; ks2 < 8; ++ks2) {
      const int goff = gc * 256 + ks2 * 32 + h * 8;   // global g elem offset
      const int gb   = ks2 * 64 + h * 16;             // sY byte col
      bf16x8 ac[4], by[4];
      {
        float4 u0 = *(const float4*)(cr0 + goff);
        float4 v0 = *(const float4*)(cr0 + goff + 4);
        float4 u1 = *(const float4*)(cr1 + goff);
        float4 v1 = *(const float4*)(cr1 + goff + 4);
        float4 u2 = *(const float4*)(cr2 + goff);
        float4 v2 = *(const float4*)(cr2 + goff + 4);
        float4 u3 = *(const float4*)(cr3 + goff);
        float4 v3 = *(const float4*)(cr3 + goff + 4);
        ac[0] = __builtin_bit_cast(bf16x8, pack8(u0, v0));
        ac[1] = __builtin_bit_cast(bf16x8, pack8(u1, v1));
        ac[2] = __builtin_bit_cast(bf16x8, pack8(u2, v2));
        ac[3] = __builtin_bit_cast(bf16x8, pack8(u3, v3));
      }
#pragma unroll
      for (int bn = 0; bn < 4; ++bn)
        by[bn] = *(const bf16x8*)(sm + (jw2 * 64 + bn * 16 + r) * 528 + gb);
#pragma unroll
      for (int bm = 0; bm < 4; ++bm)
#pragma unroll
        for (int bn = 0; bn < 4; ++bn)
          zacc[bm][bn] = __builtin_amdgcn_mfma_f32_16x16x32_bf16(
              ac[bm], by[bn], zacc[bm][bn], 0, 0, 0);
    }
  }
  __syncthreads();  // all Z-MFMA sY reads done before sZ overlay
  // dump Z (128x128) to LDS fp32, stride 132
#pragma unroll
  for (int bm = 0; bm < 4; ++bm)
#pragma unroll
    for (int bn = 0; bn < 4; ++bn)
#pragma unroll
      for (int reg = 0; reg < 4; ++reg)
        sZ[(iw * 64 + bm * 16 + h * 4 + reg) * SZS + (jw2 * 64 + bn * 16 + r)] =
            zacc[bm][bn][reg];
  __syncthreads();

  // per-row lse over j (128 cols); 4 waves x 32 rows, 2 lanes per row
  const int row = wave * 32 + (lane >> 1);
  const int c0l = lane & 1;
  float mx = -3.4e38f;
#pragma unroll
  for (int m = 0; m < 64; ++m) mx = fmaxf(mx, sZ[row * SZS + c0l + m * 2]);
  mx = fmaxf(mx, __shfl_xor(mx, 1));
  float sum = 0.f;
#pragma unroll
  for (int m = 0; m < 64; ++m) sum += __expf(sZ[row * SZS + c0l + m * 2] - mx);
  sum += __shfl_xor(sum, 1);
  float val = (c0l == 0) ? (sZ[row * SZS + row] - (__logf(sum) + mx)) : 0.f;
#pragma unroll
  for (int off = 1; off < 64; off <<= 1) val += __shfl_xor(val, off);
  if (lane == 0) sRed[wave] = val;
  __syncthreads();
  if (tid == 0) atomicAdd(out + k, sRed[0] + sRed[1] + sRed[2] + sRed[3]);
}

// ---------------- R5 fallback kernel (proven 1483 us) --------------------------
template <bool WBF>
__global__ __launch_bounds__(512, 4)
void infonce_main(const float* __restrict__ Cp, const float* __restrict__ Xp,
                  const void* __restrict__ Wp, float* __restrict__ out)
{
  __shared__ __align__(16) unsigned char smem[71680];
  unsigned short* sX = (unsigned short*)(smem);
  unsigned short* sW = (unsigned short*)(smem + 18432);
  unsigned short* sY = (unsigned short*)(smem + 36864);
  unsigned short* sC = (unsigned short*)(smem);
  float* sZ   = (float*)(smem);
  float* sRed = (float*)(smem + 67584);

  const int tid  = threadIdx.x;
  const int lane = tid & 63;
  const int wave = tid >> 6;
  const int r    = lane & 15;
  const int h    = lane >> 4;
  const int wr   = wave >> 1;
  const int wc   = wave & 1;

  const int orig = blockIdx.x;
  const int xcd  = orig & 7;
  const int loc  = orig >> 3;
  const int wg   = (xcd < 4) ? (xcd * 1024 + loc) : (4096 + (xcd - 4) * 1023 + loc);
  const int k    = wg & 3;
  const int t    = wg >> 2;
  const int tau  = 1 << k;
  if (t >= Tn - tau) return;

  const float* Cb = Cp + (size_t)t * FCn;
  const float* Xb = Xp + (size_t)(t + tau) * FXn;

  const int srow = tid >> 2;
  const int scol = (tid & 3) * 16;
  const float* xs = Xb + (size_t)srow * (Tn * FXn) + scol;
  unsigned short* xd = sX + srow * SXW + scol;
  unsigned short* wd = sW + srow * SXW + scol;
  const unsigned short* wsh = (const unsigned short*)Wp + (size_t)k * (FCn * FXn)
                              + (size_t)srow * FXn + scol;
  const float* wsf = (const float*)Wp + (size_t)k * (FCn * FXn)
                     + (size_t)srow * FXn + scol;
  const int crow0 = tid >> 4;
  const int ccol  = (tid & 15) * 8;
  const float* cs = Cb + (size_t)crow0 * (Tn * FCn) + ccol;
  unsigned short* cd = sC + crow0 * SYC + ccol;
  const size_t cstep = (size_t)32 * Tn * FCn;

  float4 px0, px1, px2, px3;
  float4 pw0, pw1, pw2, pw3;
  uint4  pb0, pb1;
  float4 pc0, pc1, pc2, pc3, pc4, pc5, pc6, pc7;

#define LOAD_X(XC) do { \
    const float4* _p = (const float4*)(xs + (XC) * 64); \
    px0 = _p[0]; px1 = _p[1]; px2 = _p[2]; px3 = _p[3]; } while (0)
#define LOAD_W(GC, XC) do { \
    if constexpr (WBF) { \
      const uint4* _p = (const uint4*)(wsh + (size_t)((GC) * 128) * FXn + (XC) * 64); \
      pb0 = _p[0]; pb1 = _p[1]; \
    } else { \
      const float4* _p = (const float4*)(wsf + (size_t)((GC) * 128) * FXn + (XC) * 64); \
      pw0 = _p[0]; pw1 = _p[1]; pw2 = _p[2]; pw3 = _p[3]; } } while (0)
#define STORE_XW() do { \
    *(uint4*)(xd)     = pack8(px0, px1); \
    *(uint4*)(xd + 8) = pack8(px2, px3); \
    if constexpr (WBF) { *(uint4*)(wd) = pb0; *(uint4*)(wd + 8) = pb1; } \
    else { *(uint4*)(wd) = pack8(pw0, pw1); *(uint4*)(wd + 8) = pack8(pw2, pw3); } \
  } while (0)
#define MFMA_Y() do { \
    _Pragma("unroll") \
    for (int ks = 0; ks < 2; ++ks) { \
      const int xoo = ks * 32 + h * 8; \
      bf16x8 a0 = *(const bf16x8*)(sX + (wr * 32 + 0  + r) * SXW + xoo); \
      bf16x8 a1 = *(const bf16x8*)(sX + (wr * 32 + 16 + r) * SXW + xoo); \
      _Pragma("unroll") \
      for (int bg = 0; bg < 4; ++bg) { \
        bf16x8 bb = *(const bf16x8*)(sW + (wc * 64 + bg * 16 + r) * SXW + xoo); \
        yacc[0][bg] = __builtin_amdgcn_mfma_f32_16x16x32_bf16(a0, bb, yacc[0][bg], 0, 0, 0); \
        yacc[1][bg] = __builtin_amdgcn_mfma_f32_16x16x32_bf16(a1, bb, yacc[1][bg], 0, 0, 0); \
      } } } while (0)

  f32x4 zacc[2][4];
#pragma unroll
  for (int a = 0; a < 2; ++a)
#pragma unroll
    for (int b = 0; b < 4; ++b) zacc[a][b] = f32x4{0.f, 0.f, 0.f, 0.f};

  LOAD_X(0); LOAD_W(0, 0);

  for (int gc = 0; gc < 4; ++gc) {
    f32x4 yacc[2][4];
#pragma unroll
    for (int a = 0; a < 2; ++a)
#pragma unroll
      for (int b = 0; b < 4; ++b) yacc[a][b] = f32x4{0.f, 0.f, 0.f, 0.f};

    for (int xc = 0; xc < 7; ++xc) {
      __syncthreads();
      STORE_XW();
      __syncthreads();
      LOAD_X(xc + 1); LOAD_W(gc, xc + 1);
      MFMA_Y();
    }
    __syncthreads();
    STORE_XW();
    __syncthreads();
    {
      const float4* p0 = (const float4*)(cs + 0 * cstep + gc * 128);
      const float4* p1 = (const float4*)(cs + 1 * cstep + gc * 128);
      const float4* p2 = (const float4*)(cs + 2 * cstep + gc * 128);
      const float4* p3 = (const float4*)(cs + 3 * cstep + gc * 128);
      pc0 = p0[0]; pc1 = p0[1];
      pc2 = p1[0]; pc3 = p1[1];
      pc4 = p2[0]; pc5 = p2[1];
      pc6 = p3[0]; pc7 = p3[1];
    }
    MFMA_Y();

#pragma unroll
    for (int aj = 0; aj < 2; ++aj)
#pragma unroll
      for (int bg = 0; bg < 4; ++bg)
#pragma unroll
        for (int reg = 0; reg < 4; ++reg)
          sY[(wr * 32 + aj * 16 + h * 4 + reg) * SYC + (wc * 64 + bg * 16 + r)] =
              (unsigned short)(__float_as_uint(yacc[aj][bg][reg]) >> 16);
    __syncthreads();
    *(uint4*)(cd + 0 * 32 * SYC) = pack8(pc0, pc1);
    *(uint4*)(cd + 1 * 32 * SYC) = pack8(pc2, pc3);
    *(uint4*)(cd + 2 * 32 * SYC) = pack8(pc4, pc5);
    *(uint4*)(cd + 3 * 32 * SYC) = pack8(pc6, pc7);
    __syncthreads();
    if (gc < 3) { LOAD_X(0); LOAD_W(gc + 1, 0); }
#pragma unroll
    for (int ks = 0; ks < 4; ++ks) {
      const int go = ks * 32 + h * 8;
      bf16x8 a0 = *(const bf16x8*)(sC + (wr * 32 + 0  + r) * SYC + go);
      bf16x8 a1 = *(const bf16x8*)(sC + (wr * 32 + 16 + r) * SYC + go);
#pragma unroll
      for (int bj = 0; bj < 4; ++bj) {
        bf16x8 bb = *(const bf16x8*)(sY + (wc * 64 + bj * 16 + r) * SYC + go);
        zacc[0][bj] = __builtin_amdgcn_mfma_f32_16x16x32_bf16(a0, bb, zacc[0][bj], 0, 0, 0);
        zacc[1][bj] = __builtin_amdgcn_mfma_f32_16x16x32_bf16(a1, bb, zacc[1][bj], 0, 0, 0);
      }
    }
  }
  __syncthreads();
#pragma unroll
  for (int ai = 0; ai < 2; ++ai)
#pragma unroll
    for (int bj = 0; bj < 4; ++bj)
#pragma unroll
      for (int reg = 0; reg < 4; ++reg)
        sZ[(wr * 32 + ai * 16 + h * 4 + reg) * SZS + (wc * 64 + bj * 16 + r)] =
            zacc[ai][bj][reg];
  __syncthreads();

  const int row = wave * 16 + (lane >> 2);
  const int c0l = lane & 3;
  float mx = -3.4e38f;
#pragma unroll
  for (int m = 0; m < 32; ++m) mx = fmaxf(mx, sZ[row * SZS + c0l + m * 4]);
  mx = fmaxf(mx, __shfl_xor(mx, 1));
  mx = fmaxf(mx, __shfl_xor(mx, 2));
  float sum = 0.f;
#pragma unroll
  for (int m = 0; m < 32; ++m) sum += __expf(sZ[row * SZS + c0l + m * 4] - mx);
  sum += __shfl_xor(sum, 1);
  sum += __shfl_xor(sum, 2);
  float val = (c0l == 0) ? (sZ[row * SZS + row] - (__logf(sum) + mx)) : 0.f;
#pragma unroll
  for (int off = 1; off < 64; off <<= 1) val += __shfl_xor(val, off);
  if (lane == 0) sRed[wave] = val;
  __syncthreads();
  if (tid == 0) {
    float bs = 0.f;
#pragma unroll
    for (int w2 = 0; w2 < 8; ++w2) bs += sRed[w2];
    atomicAdd(out + k, bs);
  }
#undef LOAD_X
#undef LOAD_W
#undef STORE_XW
#undef MFMA_Y
}

extern "C" void kernel_launch(void* const* d_in, const int* in_sizes, int n_in,
                              void* d_out, int out_size, void* d_ws, size_t ws_size,
                              hipStream_t stream) {
  const float* C = (const float*)d_in[0];
  const float* X = (const float*)d_in[1];
  const float* W = (const float*)d_in[2];
  // d_in[3] (bias) intentionally unused: j-independent bias cancels in Zdiag - lse
  float* out = (float*)d_out;

  const size_t NX = (size_t)128 * Tn * FXn;        // 134,217,728 elems (X)
  const size_t NW = (size_t)4 * FCn * FXn;         // 1,048,576 elems
  const size_t WS_W   = NW * 2;                    // 2 MB
  const size_t WS_MID = WS_W + NX * 2;             // + Xbf = 270,532,608

  hipLaunchKernelGGL(zero4, dim3(1), dim3(64), 0, stream, out);

  if (ws_size >= WS_MID) {
    unsigned short* Wbf = (unsigned short*)d_ws;
    unsigned short* Xbf = (unsigned short*)((char*)d_ws + WS_W);
    hipLaunchKernelGGL(tobf16, dim3((unsigned)(NW / 1024)), dim3(256), 0, stream, W, Wbf);
    hipLaunchKernelGGL(tobf16, dim3((unsigned)(NX / 1024)), dim3(256), 0, stream, X, Xbf);
    hipLaunchKernelGGL(infonce_v7, dim3(2047 * 4), dim3(256), 0, stream,
                       C, Xbf, Wbf, out);
  } else if (ws_size >= WS_W) {
    hipLaunchKernelGGL(tobf16, dim3((unsigned)(NW / 1024)), dim3(256), 0, stream,
                       W, (unsigned short*)d_ws);
    hipLaunchKernelGGL(infonce_main<true>, dim3(2047 * 4), dim3(512), 0, stream,
                       C, X, (const void*)d_ws, out);
  } else {
    hipLaunchKernelGGL(infonce_main<false>, dim3(2047 * 4), dim3(512), 0, stream,
                       C, X, (const void*)W, out);
  }
  hipLaunchKernelGGL(finalize4, dim3(1), dim3(64), 0, stream, out);
}